// Round 4
// baseline (111.542 us; speedup 1.0000x reference)
//
#include <hip/hip_runtime.h>
#include <math.h>

// Problem constants (RelTransformerActor)
namespace {
constexpr int B_  = 128;
constexpr int T_  = 128;
constexpr int K_  = 8;
constexpr int H_  = 3;
constexpr int HK_ = 24;
constexpr int HID_ = 256;
constexpr int OUT_ = 2;
}

typedef __attribute__((ext_vector_type(8))) short bf16x8;
typedef __attribute__((ext_vector_type(4))) float f32x4;

__device__ inline unsigned short f2bf(float x) {           // RNE fp32->bf16
    unsigned int u = __float_as_uint(x);
    u += 0x7FFFu + ((u >> 16) & 1u);
    return (unsigned short)(u >> 16);
}
__device__ inline float bflo(unsigned int u) { return __uint_as_float(u << 16); }
__device__ inline float bfhi(unsigned int u) { return __uint_as_float(u & 0xFFFF0000u); }

// ---------------------------------------------------------------------------
// Prep: W1 [32][256] -> w1t bf16 [n][k=32]; W2 [256][256] -> w2t bf16 [n][k=256]
// (B-fragment layout for mfma_16x16x32_bf16 needs k-contiguous rows per n).
// 8 k's per thread: coalesced reads over n, one b128 write per thread.
// ---------------------------------------------------------------------------
__global__ __launch_bounds__(256) void prep_kernel(
    const float* __restrict__ W1, const float* __restrict__ W2,
    unsigned short* __restrict__ w1t, unsigned short* __restrict__ w2t)
{
    const int n = threadIdx.x;
    unsigned short tmp[8];
    if (blockIdx.x < 32) {
        const int k0 = blockIdx.x * 8;
        #pragma unroll
        for (int i = 0; i < 8; ++i) tmp[i] = f2bf(W2[(size_t)(k0+i)*HID_ + n]);
        *(bf16x8*)(w2t + (size_t)n*256 + k0) = *(const bf16x8*)tmp;
    } else {
        const int k0 = (blockIdx.x - 32) * 8;
        #pragma unroll
        for (int i = 0; i < 8; ++i) tmp[i] = f2bf(W1[(size_t)(k0+i)*HID_ + n]);
        *(bf16x8*)(w1t + (size_t)n*32 + k0) = *(const bf16x8*)tmp;
    }
}

// ---------------------------------------------------------------------------
// Fused actor. Block = (b, eighth of i): 16 query rows, 256 threads,
// ~35 KB LDS -> 4 blocks/CU co-resident (latency hiding across barriers).
// Attention identities: softmax shift-invariance kills Kp[i]; sum w = 1
// turns the Vp[i] term into a subtraction.
// ---------------------------------------------------------------------------
__global__ __launch_bounds__(256) void fused_actor_kernel(
    const float* __restrict__ state,
    const float* __restrict__ noise,
    const float* __restrict__ Wq, const float* __restrict__ Wk,
    const float* __restrict__ Wv,
    const unsigned short* __restrict__ w1t, const float* __restrict__ b1,
    const unsigned short* __restrict__ w2t, const float* __restrict__ b2,
    const float* __restrict__ Wmu, const float* __restrict__ bmu,
    const float* __restrict__ Wls, const float* __restrict__ bls,
    float* __restrict__ out)
{
    __shared__ alignas(16) float st[T_][K_];                 // 4 KB
    __shared__ float wq_s[K_*HK_], wk_s[K_*HK_], wv_s[K_*HK_]; // 2.25 KB
    __shared__ alignas(16) float Qs[16][HK_];                // 1.5 KB (row 96B)
    __shared__ alignas(16) unsigned short Kb[H_][T_][8];     // 6 KB (row 16B)
    __shared__ alignas(16) unsigned short Vb[H_][T_][8];     // 6 KB
    __shared__ alignas(16) unsigned short a0b[16][40];       // 1.25 KB (row 80B)
    __shared__ alignas(16) unsigned short x1s[16][264];      // 8.25 KB (row 528B)
    __shared__ alignas(16) float Whs[HID_][4];               // 4 KB
    __shared__ alignas(16) float hp[4][16][4];               // 1 KB

    const int tid = threadIdx.x;
    const int b   = blockIdx.x >> 3;
    const int iq  = blockIdx.x & 7;          // 16-row slice: rows iq*16..+16

    // ---- stage state + tiny weights ----
    ((float4*)&st[0][0])[tid] = ((const float4*)(state + (size_t)b*T_*K_))[tid];
    if (tid < K_*HK_) { wq_s[tid]=Wq[tid]; wk_s[tid]=Wk[tid]; wv_s[tid]=Wv[tid]; }
    { f32x4 wh = { Wmu[tid*OUT_+0], Wmu[tid*OUT_+1], Wls[tid*OUT_+0], Wls[tid*OUT_+1] };
      *(f32x4*)&Whs[tid][0] = wh; }
    __syncthreads();

    // ---- projections ----
    if (tid < 128) {
        // thread = j: K/V projections, weights broadcast from LDS
        const int j = tid;
        const float4 s0 = *(const float4*)(state + (size_t)b*T_*K_ + j*8);
        const float4 s1 = *(const float4*)(state + (size_t)b*T_*K_ + j*8 + 4);
        const float sv[8] = {s0.x,s0.y,s0.z,s0.w,s1.x,s1.y,s1.z,s1.w};
        #pragma unroll
        for (int h = 0; h < H_; ++h) {
            unsigned short kp[8], vp[8];
            #pragma unroll
            for (int k = 0; k < 8; ++k) {
                const int col = h*8 + k;
                float ak = 0.f, av = 0.f;
                #pragma unroll
                for (int m = 0; m < K_; ++m) {
                    ak = fmaf(sv[m], wk_s[m*HK_+col], ak);
                    av = fmaf(sv[m], wv_s[m*HK_+col], av);
                }
                kp[k] = f2bf(ak); vp[k] = f2bf(av);
            }
            *(bf16x8*)&Kb[h][j][0] = *(const bf16x8*)kp;   // lanes consecutive rows
            *(bf16x8*)&Vb[h][j][0] = *(const bf16x8*)vp;
        }
    } else {
        // thread covers 3 Q columns of one of the block's 16 rows
        const int t2 = tid - 128;
        const int il = t2 >> 3;
        const int c0 = (t2 & 7) * 3;
        const float4 s0 = *(const float4*)&st[iq*16 + il][0];
        const float4 s1 = *(const float4*)&st[iq*16 + il][4];
        const float sv[8] = {s0.x,s0.y,s0.z,s0.w,s1.x,s1.y,s1.z,s1.w};
        #pragma unroll
        for (int cc = 0; cc < 3; ++cc) {
            const int col = c0 + cc;
            float aq = 0.f;
            #pragma unroll
            for (int m = 0; m < K_; ++m) aq = fmaf(sv[m], wq_s[m*HK_+col], aq);
            Qs[il][col] = aq * 0.35355339059327373f;
        }
    }
    __syncthreads();

    const int w    = tid >> 6;
    const int lane = tid & 63;

    // ---- attention: lane=(i_sub*16+jg); 3 passes/wave; 4-step butterfly ----
    {
        const int i_sub = lane >> 4, jg = lane & 15;
        #pragma unroll
        for (int p = 0; p < 3; ++p) {
            const int pp = w*3 + p;          // 0..11 : (h, group-of-4-i)
            const int h  = pp >> 2;
            const int ig = pp & 3;
            const int il = ig*4 + i_sub;
            const int iglob = iq*16 + il;
            const float4 q0 = *(const float4*)&Qs[il][h*8];
            const float4 q1 = *(const float4*)&Qs[il][h*8+4];
            float l = 0.f;
            float acc[8] = {0.f,0.f,0.f,0.f,0.f,0.f,0.f,0.f};
            #pragma unroll
            for (int t = 0; t < 8; ++t) {
                const int j = t*16 + jg;     // 16 consecutive rows -> 256B/instr
                const int4 kk = *(const int4*)&Kb[h][j][0];
                float s;
                s = q0.x * bflo(kk.x) + q0.y * bfhi(kk.x)
                  + q0.z * bflo(kk.y) + q0.w * bfhi(kk.y)
                  + q1.x * bflo(kk.z) + q1.y * bfhi(kk.z)
                  + q1.z * bflo(kk.w) + q1.w * bfhi(kk.w);
                const float e = (j == iglob) ? 0.f : __expf(s);
                l += e;
                const int4 vv = *(const int4*)&Vb[h][j][0];
                acc[0] = fmaf(e, bflo(vv.x), acc[0]);
                acc[1] = fmaf(e, bfhi(vv.x), acc[1]);
                acc[2] = fmaf(e, bflo(vv.y), acc[2]);
                acc[3] = fmaf(e, bfhi(vv.y), acc[3]);
                acc[4] = fmaf(e, bflo(vv.z), acc[4]);
                acc[5] = fmaf(e, bfhi(vv.z), acc[5]);
                acc[6] = fmaf(e, bflo(vv.w), acc[6]);
                acc[7] = fmaf(e, bfhi(vv.w), acc[7]);
            }
            #pragma unroll
            for (int off = 1; off <= 8; off <<= 1) {
                l += __shfl_xor(l, off, 64);
                #pragma unroll
                for (int k = 0; k < 8; ++k) acc[k] += __shfl_xor(acc[k], off, 64);
            }
            if (jg == 0) {
                const float rl = 1.f / l;
                const int4 vi = *(const int4*)&Vb[h][iglob][0];
                const float vs[8] = { bflo(vi.x), bfhi(vi.x), bflo(vi.y), bfhi(vi.y),
                                      bflo(vi.z), bfhi(vi.z), bflo(vi.w), bfhi(vi.w) };
                unsigned int r01 = (unsigned int)f2bf(acc[0]*rl - vs[0])
                                 | ((unsigned int)f2bf(acc[1]*rl - vs[1]) << 16);
                unsigned int r23 = (unsigned int)f2bf(acc[2]*rl - vs[2])
                                 | ((unsigned int)f2bf(acc[3]*rl - vs[3]) << 16);
                unsigned int r45 = (unsigned int)f2bf(acc[4]*rl - vs[4])
                                 | ((unsigned int)f2bf(acc[5]*rl - vs[5]) << 16);
                unsigned int r67 = (unsigned int)f2bf(acc[6]*rl - vs[6])
                                 | ((unsigned int)f2bf(acc[7]*rl - vs[7]) << 16);
                int4 rr; rr.x = r01; rr.y = r23; rr.z = r45; rr.w = r67;
                *(int4*)&a0b[il][h*8] = rr;
            }
        }
    }
    // concat state (bf16) into a0b cols 24..31 (threads 0..127)
    if (tid < 128) {
        const int il = tid >> 3, k = tid & 7;
        a0b[il][HK_ + k] = f2bf(st[iq*16 + il][k]);
    }
    __syncthreads();

    const int lq = (tid >> 4) & 3;   // MFMA k-chunk (A/B) / row-group (D)
    const int ln = tid & 15;         // MFMA m (A) / n (B,D)

    // ---- x1 = relu([x||state] @ W1 + b1) via MFMA, M=16, K=32 ----
    {
        const bf16x8 a0 = *(const bf16x8*)&a0b[ln][lq*8];
        #pragma unroll
        for (int nt = 0; nt < 4; ++nt) {
            const int n0 = (w*4 + nt)*16;
            const bf16x8 bf = *(const bf16x8*)(w1t + (size_t)(n0+ln)*32 + lq*8);
            const float bias = b1[n0+ln];
            f32x4 c = {bias, bias, bias, bias};
            f32x4 d = __builtin_amdgcn_mfma_f32_16x16x32_bf16(a0, bf, c, 0, 0, 0);
            #pragma unroll
            for (int r = 0; r < 4; ++r)
                x1s[lq*4 + r][n0+ln] = f2bf(fmaxf(d[r], 0.f));
        }
    }
    __syncthreads();

    // ---- x2 = relu(x1 @ W2 + b2) via MFMA: 4 N-tiles x 8 k-steps ----
    f32x4 acc2[4];
    #pragma unroll
    for (int nt = 0; nt < 4; ++nt) {
        const float bias = b2[(w*4+nt)*16 + ln];
        f32x4 c = {bias, bias, bias, bias};
        acc2[nt] = c;
    }
    #pragma unroll 2
    for (int ks = 0; ks < 8; ++ks) {
        const int k0 = ks*32;
        const bf16x8 a0 = *(const bf16x8*)&x1s[ln][k0 + lq*8];
        #pragma unroll
        for (int nt = 0; nt < 4; ++nt) {
            const bf16x8 bf = *(const bf16x8*)(w2t + (size_t)((w*4+nt)*16+ln)*256 + k0 + lq*8);
            acc2[nt] = __builtin_amdgcn_mfma_f32_16x16x32_bf16(a0, bf, acc2[nt], 0, 0, 0);
        }
    }

    // ---- heads: relu(x2) . {Wmu,Wls}, reduce over 16 n-lanes ----
    {
        float p[4][4];
        #pragma unroll
        for (int r = 0; r < 4; ++r)
            #pragma unroll
            for (int o = 0; o < 4; ++o) p[r][o] = 0.f;
        #pragma unroll
        for (int nt = 0; nt < 4; ++nt) {
            const int n = (w*4+nt)*16 + ln;
            const f32x4 wh = *(const f32x4*)&Whs[n][0];
            #pragma unroll
            for (int r = 0; r < 4; ++r) {
                const float x2 = fmaxf(acc2[nt][r], 0.f);
                p[r][0] = fmaf(x2, wh[0], p[r][0]);
                p[r][1] = fmaf(x2, wh[1], p[r][1]);
                p[r][2] = fmaf(x2, wh[2], p[r][2]);
                p[r][3] = fmaf(x2, wh[3], p[r][3]);
            }
        }
        #pragma unroll
        for (int off = 1; off <= 8; off <<= 1)
            #pragma unroll
            for (int r = 0; r < 4; ++r)
                #pragma unroll
                for (int o = 0; o < 4; ++o)
                    p[r][o] += __shfl_xor(p[r][o], off, 64);
        if (ln == 0) {
            #pragma unroll
            for (int r = 0; r < 4; ++r) {
                f32x4 pv = {p[r][0], p[r][1], p[r][2], p[r][3]};
                *(f32x4*)&hp[w][lq*4 + r][0] = pv;
            }
        }
    }
    __syncthreads();

    // ---- sampling tail: one thread per row ----
    if (tid < 16) {
        const int r = tid;
        const int grow = b*T_ + iq*16 + r;
        float pre[4];
        #pragma unroll
        for (int o = 0; o < 4; ++o)
            pre[o] = hp[0][r][o] + hp[1][r][o] + hp[2][r][o] + hp[3][r][o];
        float lp = 0.f;
        #pragma unroll
        for (int o = 0; o < OUT_; ++o) {
            float mu  = tanhf(pre[o]   + bmu[o]);
            float lsp = tanhf(pre[2+o] + bls[o]);
            float log_std = -20.f + 11.f * (lsp + 1.f);
            float sd = __expf(log_std);
            float n  = noise[(size_t)grow*OUT_ + o];
            float z  = fmaf(sd, n, mu);
            float a  = tanhf(z);
            out[(size_t)grow*OUT_ + o] = a;
            lp += -0.5f*n*n - log_std - 0.91893853320467274f
                  - logf(1.f - a*a + 1e-7f);
        }
        out[(size_t)B_*T_*OUT_ + grow] = lp;
    }
}

extern "C" void kernel_launch(void* const* d_in, const int* in_sizes, int n_in,
                              void* d_out, int out_size, void* d_ws, size_t ws_size,
                              hipStream_t stream)
{
    const float* state = (const float*)d_in[0];
    const float* noise = (const float*)d_in[1];
    const float* Wq  = (const float*)d_in[2];
    const float* Wk  = (const float*)d_in[3];
    const float* Wv  = (const float*)d_in[4];
    const float* W1  = (const float*)d_in[5];
    const float* b1  = (const float*)d_in[6];
    const float* W2  = (const float*)d_in[7];
    const float* b2  = (const float*)d_in[8];
    const float* Wmu = (const float*)d_in[9];
    const float* bmu = (const float*)d_in[10];
    const float* Wls = (const float*)d_in[11];
    const float* bls = (const float*)d_in[12];
    float* out = (float*)d_out;

    unsigned short* w1t = (unsigned short*)d_ws;            // 8192  bf16 = 16 KB
    unsigned short* w2t = w1t + 8192;                       // 65536 bf16 = 128 KB

    prep_kernel<<<dim3(36), dim3(256), 0, stream>>>(W1, W2, w1t, w2t);
    fused_actor_kernel<<<dim3(B_*8), dim3(256), 0, stream>>>(
        state, noise, Wq, Wk, Wv, w1t, b1, w2t, b2, Wmu, bmu, Wls, bls, out);
}

// Round 5
// 106.925 us; speedup vs baseline: 1.0432x; 1.0432x over previous
//
#include <hip/hip_runtime.h>
#include <math.h>

// Problem constants (RelTransformerActor)
namespace {
constexpr int B_  = 128;
constexpr int T_  = 128;
constexpr int K_  = 8;
constexpr int H_  = 3;
constexpr int HK_ = 24;
constexpr int HID_ = 256;
constexpr int OUT_ = 2;
}

typedef __attribute__((ext_vector_type(8))) short bf16x8;
typedef __attribute__((ext_vector_type(4))) float f32x4;

__device__ inline unsigned short f2bf(float x) {           // RNE fp32->bf16
    unsigned int u = __float_as_uint(x);
    u += 0x7FFFu + ((u >> 16) & 1u);
    return (unsigned short)(u >> 16);
}
__device__ inline float bflo(unsigned int u) { return __uint_as_float(u << 16); }
__device__ inline float bfhi(unsigned int u) { return __uint_as_float(u & 0xFFFF0000u); }

// Cross-lane add via DPP (VALU pipe, not DS). Patterns:
// 0xB1 = quad_perm lane^1, 0x4E = quad_perm lane^2,
// 0x141 = row_half_mirror (pairs with the other quad within each 8),
// 0x140 = row_mirror (pairs with the other 8 within each 16).
template <int CTRL>
__device__ inline float dpp_add(float v) {
    int t = __builtin_amdgcn_update_dpp(0, __float_as_int(v), CTRL, 0xF, 0xF, true);
    return v + __int_as_float(t);
}
__device__ inline float red8(float v) {    // sum over 8-lane groups
    v = dpp_add<0xB1>(v); v = dpp_add<0x4E>(v); return dpp_add<0x141>(v);
}
__device__ inline float red16(float v) {   // sum over 16-lane groups
    return dpp_add<0x140>(red8(v));
}

// ---------------------------------------------------------------------------
// Prep kernel.
//  blocks 0..31 : W2 [256][256] -> w2t bf16 [n][k=256]  (MFMA B-frag layout)
//  blocks 32..35: W1 [32][256]  -> w1t bf16 [n][k=32]
//  blocks 36..163: per-b projections (identities applied):
//    kb[b][h][j][8], vb[b][h][j][8] (bf16), qsc[b][i][24] (fp32, * 1/sqrt(8))
// ---------------------------------------------------------------------------
__global__ __launch_bounds__(256) void prep_kernel(
    const float* __restrict__ state,
    const float* __restrict__ Wq, const float* __restrict__ Wk,
    const float* __restrict__ Wv,
    const float* __restrict__ W1, const float* __restrict__ W2,
    unsigned short* __restrict__ w1t, unsigned short* __restrict__ w2t,
    unsigned short* __restrict__ kb, unsigned short* __restrict__ vb,
    float* __restrict__ qsc)
{
    __shared__ float wq_s[K_*HK_], wk_s[K_*HK_], wv_s[K_*HK_];
    const int tid = threadIdx.x;
    const int blk = blockIdx.x;

    if (blk < 32) {                          // W2 transpose
        const int k0 = blk * 8;
        unsigned short tmp[8];
        #pragma unroll
        for (int i = 0; i < 8; ++i) tmp[i] = f2bf(W2[(size_t)(k0+i)*HID_ + tid]);
        *(bf16x8*)(w2t + (size_t)tid*256 + k0) = *(const bf16x8*)tmp;
        return;
    }
    if (blk < 36) {                          // W1 transpose
        const int k0 = (blk - 32) * 8;
        unsigned short tmp[8];
        #pragma unroll
        for (int i = 0; i < 8; ++i) tmp[i] = f2bf(W1[(size_t)(k0+i)*HID_ + tid]);
        *(bf16x8*)(w1t + (size_t)tid*32 + k0) = *(const bf16x8*)tmp;
        return;
    }

    const int b = blk - 36;
    if (tid < K_*HK_) { wq_s[tid]=Wq[tid]; wk_s[tid]=Wk[tid]; wv_s[tid]=Wv[tid]; }
    __syncthreads();

    const float* sb = state + (size_t)b*T_*K_;
    if (tid < 128) {
        // thread = j: K/V projections, bf16-packed global writes
        const int j = tid;
        const float4 s0 = *(const float4*)(sb + j*8);
        const float4 s1 = *(const float4*)(sb + j*8 + 4);
        const float sv[8] = {s0.x,s0.y,s0.z,s0.w,s1.x,s1.y,s1.z,s1.w};
        #pragma unroll
        for (int h = 0; h < H_; ++h) {
            unsigned short kp[8], vp[8];
            #pragma unroll
            for (int k = 0; k < 8; ++k) {
                const int col = h*8 + k;
                float ak = 0.f, av = 0.f;
                #pragma unroll
                for (int m = 0; m < K_; ++m) {
                    ak = fmaf(sv[m], wk_s[m*HK_+col], ak);
                    av = fmaf(sv[m], wv_s[m*HK_+col], av);
                }
                kp[k] = f2bf(ak); vp[k] = f2bf(av);
            }
            const size_t off = ((size_t)(b*H_ + h)*T_ + j) * 8;
            *(bf16x8*)(kb + off) = *(const bf16x8*)kp;
            *(bf16x8*)(vb + off) = *(const bf16x8*)vp;
        }
    } else {
        // thread = i: Q projection (fp32, pre-scaled by 1/sqrt(8))
        const int i = tid - 128;
        const float4 s0 = *(const float4*)(sb + i*8);
        const float4 s1 = *(const float4*)(sb + i*8 + 4);
        const float sv[8] = {s0.x,s0.y,s0.z,s0.w,s1.x,s1.y,s1.z,s1.w};
        float q[HK_];
        #pragma unroll
        for (int col = 0; col < HK_; ++col) {
            float aq = 0.f;
            #pragma unroll
            for (int m = 0; m < K_; ++m) aq = fmaf(sv[m], wq_s[m*HK_+col], aq);
            q[col] = aq * 0.35355339059327373f;
        }
        float* qo = qsc + (size_t)(b*T_ + i)*HK_;
        #pragma unroll
        for (int c = 0; c < 6; ++c)
            *(float4*)(qo + c*4) = *(const float4*)&q[c*4];
    }
}

// ---------------------------------------------------------------------------
// Fused actor. Block = (b, quarter of i): 32 query rows, 256 threads.
// All projections precomputed; K/V/Q read from global (L1/L2-resident).
// Attention identities: softmax shift-invariance kills Kp[i]; sum w = 1
// turns the Vp[i] term into a subtraction. Reductions via DPP (VALU).
// ---------------------------------------------------------------------------
__global__ __launch_bounds__(256) void fused_actor_kernel(
    const float* __restrict__ state,
    const float* __restrict__ noise,
    const unsigned short* __restrict__ kb, const unsigned short* __restrict__ vb,
    const float* __restrict__ qsc,
    const unsigned short* __restrict__ w1t, const float* __restrict__ b1,
    const unsigned short* __restrict__ w2t, const float* __restrict__ b2,
    const float* __restrict__ Wmu, const float* __restrict__ bmu,
    const float* __restrict__ Wls, const float* __restrict__ bls,
    float* __restrict__ out)
{
    __shared__ alignas(16) unsigned short a0b[32][40];   // 2.5 KB (row 80B)
    __shared__ alignas(16) unsigned short x1s[32][264];  // 16.5 KB (row 528B)
    __shared__ alignas(16) float hp[4][32][4];           // 2 KB

    const int tid  = threadIdx.x;
    const int b    = blockIdx.x >> 2;
    const int iq   = blockIdx.x & 3;
    const int i0   = iq * 32;
    const int w    = tid >> 6;
    const int lane = tid & 63;

    // ---- attention: lane=(i_sub*8+jg); 3 passes/wave; DPP 8-lane reduce ----
    {
        const int i_sub = lane >> 3, jg = lane & 7;
        #pragma unroll
        for (int p = 0; p < 3; ++p) {
            const int pair = w*3 + p;        // 0..11 : (h, group-of-8-i)
            const int h  = pair >> 2;
            const int ig = pair & 3;
            const int il = ig*8 + i_sub;
            const int iglob = i0 + il;
            const float* qp = qsc + (size_t)(b*T_ + iglob)*HK_ + h*8;
            const float4 q0 = *(const float4*)qp;
            const float4 q1 = *(const float4*)(qp + 4);
            const unsigned short* kbase = kb + (size_t)(b*H_ + h)*T_*8;
            const unsigned short* vbase = vb + (size_t)(b*H_ + h)*T_*8;
            float l = 0.f;
            float acc[8] = {0.f,0.f,0.f,0.f,0.f,0.f,0.f,0.f};
            #pragma unroll 4
            for (int t = 0; t < 16; ++t) {
                const int j = t*8 + jg;      // 8 lanes -> 128B contiguous
                const int4 kk = *(const int4*)(kbase + j*8);
                float s;
                s = q0.x * bflo(kk.x) + q0.y * bfhi(kk.x)
                  + q0.z * bflo(kk.y) + q0.w * bfhi(kk.y)
                  + q1.x * bflo(kk.z) + q1.y * bfhi(kk.z)
                  + q1.z * bflo(kk.w) + q1.w * bfhi(kk.w);
                const float e = (j == iglob) ? 0.f : __expf(s);
                l += e;
                const int4 vv = *(const int4*)(vbase + j*8);
                acc[0] = fmaf(e, bflo(vv.x), acc[0]);
                acc[1] = fmaf(e, bfhi(vv.x), acc[1]);
                acc[2] = fmaf(e, bflo(vv.y), acc[2]);
                acc[3] = fmaf(e, bfhi(vv.y), acc[3]);
                acc[4] = fmaf(e, bflo(vv.z), acc[4]);
                acc[5] = fmaf(e, bfhi(vv.z), acc[5]);
                acc[6] = fmaf(e, bflo(vv.w), acc[6]);
                acc[7] = fmaf(e, bfhi(vv.w), acc[7]);
            }
            l = red8(l);
            #pragma unroll
            for (int k = 0; k < 8; ++k) acc[k] = red8(acc[k]);
            if (jg == 0) {
                const float rl = 1.f / l;
                const int4 vi = *(const int4*)(vbase + iglob*8);
                const float vs[8] = { bflo(vi.x), bfhi(vi.x), bflo(vi.y), bfhi(vi.y),
                                      bflo(vi.z), bfhi(vi.z), bflo(vi.w), bfhi(vi.w) };
                unsigned int r01 = (unsigned int)f2bf(acc[0]*rl - vs[0])
                                 | ((unsigned int)f2bf(acc[1]*rl - vs[1]) << 16);
                unsigned int r23 = (unsigned int)f2bf(acc[2]*rl - vs[2])
                                 | ((unsigned int)f2bf(acc[3]*rl - vs[3]) << 16);
                unsigned int r45 = (unsigned int)f2bf(acc[4]*rl - vs[4])
                                 | ((unsigned int)f2bf(acc[5]*rl - vs[5]) << 16);
                unsigned int r67 = (unsigned int)f2bf(acc[6]*rl - vs[6])
                                 | ((unsigned int)f2bf(acc[7]*rl - vs[7]) << 16);
                int4 rr; rr.x = r01; rr.y = r23; rr.z = r45; rr.w = r67;
                *(int4*)&a0b[il][h*8] = rr;
            }
        }
    }
    // concat state (bf16) into a0b cols 24..31
    {
        const int il = tid >> 3, k = tid & 7;
        a0b[il][HK_ + k] = f2bf(state[(size_t)b*T_*K_ + (i0 + il)*K_ + k]);
    }
    __syncthreads();

    const int lq = (tid >> 4) & 3;   // MFMA k-chunk (A/B) / row-group (D)
    const int ln = tid & 15;         // MFMA m (A) / n (B,D)

    // ---- x1 = relu([x||state] @ W1 + b1) via MFMA, M=32 (2 tiles), K=32 ----
    {
        const bf16x8 a0 = *(const bf16x8*)&a0b[ln][lq*8];
        const bf16x8 a1 = *(const bf16x8*)&a0b[16+ln][lq*8];
        #pragma unroll
        for (int nt = 0; nt < 4; ++nt) {
            const int n0 = (w*4 + nt)*16;
            const bf16x8 bf = *(const bf16x8*)(w1t + (size_t)(n0+ln)*32 + lq*8);
            const float bias = b1[n0+ln];
            f32x4 c = {bias, bias, bias, bias};
            f32x4 d0 = __builtin_amdgcn_mfma_f32_16x16x32_bf16(a0, bf, c, 0, 0, 0);
            f32x4 d1 = __builtin_amdgcn_mfma_f32_16x16x32_bf16(a1, bf, c, 0, 0, 0);
            #pragma unroll
            for (int r = 0; r < 4; ++r) {
                x1s[lq*4 + r][n0+ln]      = f2bf(fmaxf(d0[r], 0.f));
                x1s[16 + lq*4 + r][n0+ln] = f2bf(fmaxf(d1[r], 0.f));
            }
        }
    }
    __syncthreads();

    // ---- x2 = relu(x1 @ W2 + b2) via MFMA: 2 M-tiles x 4 N-tiles x 8 k ----
    f32x4 acc2[2][4];
    #pragma unroll
    for (int nt = 0; nt < 4; ++nt) {
        const float bias = b2[(w*4+nt)*16 + ln];
        f32x4 c = {bias, bias, bias, bias};
        acc2[0][nt] = c; acc2[1][nt] = c;
    }
    #pragma unroll 2
    for (int ks = 0; ks < 8; ++ks) {
        const int k0 = ks*32;
        const bf16x8 a0 = *(const bf16x8*)&x1s[ln][k0 + lq*8];
        const bf16x8 a1 = *(const bf16x8*)&x1s[16+ln][k0 + lq*8];
        #pragma unroll
        for (int nt = 0; nt < 4; ++nt) {
            const bf16x8 bf = *(const bf16x8*)(w2t + (size_t)((w*4+nt)*16+ln)*256 + k0 + lq*8);
            acc2[0][nt] = __builtin_amdgcn_mfma_f32_16x16x32_bf16(a0, bf, acc2[0][nt], 0,0,0);
            acc2[1][nt] = __builtin_amdgcn_mfma_f32_16x16x32_bf16(a1, bf, acc2[1][nt], 0,0,0);
        }
    }

    // ---- heads: relu(x2).{Wmu,Wls}; DPP 16-lane reduce over n-lanes ----
    {
        float p[2][4][4];
        #pragma unroll
        for (int mt = 0; mt < 2; ++mt)
            #pragma unroll
            for (int r = 0; r < 4; ++r)
                #pragma unroll
                for (int o = 0; o < 4; ++o) p[mt][r][o] = 0.f;
        #pragma unroll
        for (int nt = 0; nt < 4; ++nt) {
            const int n = (w*4+nt)*16 + ln;
            const float2 wm = *(const float2*)(Wmu + n*OUT_);
            const float2 wl = *(const float2*)(Wls + n*OUT_);
            #pragma unroll
            for (int mt = 0; mt < 2; ++mt) {
                #pragma unroll
                for (int r = 0; r < 4; ++r) {
                    const float x2 = fmaxf(acc2[mt][nt][r], 0.f);
                    p[mt][r][0] = fmaf(x2, wm.x, p[mt][r][0]);
                    p[mt][r][1] = fmaf(x2, wm.y, p[mt][r][1]);
                    p[mt][r][2] = fmaf(x2, wl.x, p[mt][r][2]);
                    p[mt][r][3] = fmaf(x2, wl.y, p[mt][r][3]);
                }
            }
        }
        #pragma unroll
        for (int mt = 0; mt < 2; ++mt)
            #pragma unroll
            for (int r = 0; r < 4; ++r)
                #pragma unroll
                for (int o = 0; o < 4; ++o)
                    p[mt][r][o] = red16(p[mt][r][o]);
        if (ln == 0) {
            #pragma unroll
            for (int mt = 0; mt < 2; ++mt)
                #pragma unroll
                for (int r = 0; r < 4; ++r) {
                    f32x4 pv = {p[mt][r][0], p[mt][r][1], p[mt][r][2], p[mt][r][3]};
                    *(f32x4*)&hp[w][mt*16 + lq*4 + r][0] = pv;
                }
        }
    }
    __syncthreads();

    // ---- sampling tail: one thread per row ----
    if (tid < 32) {
        const int r = tid;
        const int grow = b*T_ + i0 + r;
        float pre[4];
        #pragma unroll
        for (int o = 0; o < 4; ++o)
            pre[o] = hp[0][r][o] + hp[1][r][o] + hp[2][r][o] + hp[3][r][o];
        float lp = 0.f;
        #pragma unroll
        for (int o = 0; o < OUT_; ++o) {
            float mu  = tanhf(pre[o]   + bmu[o]);
            float lsp = tanhf(pre[2+o] + bls[o]);
            float log_std = -20.f + 11.f * (lsp + 1.f);
            float sd = __expf(log_std);
            float n  = noise[(size_t)grow*OUT_ + o];
            float z  = fmaf(sd, n, mu);
            float a  = tanhf(z);
            out[(size_t)grow*OUT_ + o] = a;
            lp += -0.5f*n*n - log_std - 0.91893853320467274f
                  - logf(1.f - a*a + 1e-7f);
        }
        out[(size_t)B_*T_*OUT_ + grow] = lp;
    }
}

extern "C" void kernel_launch(void* const* d_in, const int* in_sizes, int n_in,
                              void* d_out, int out_size, void* d_ws, size_t ws_size,
                              hipStream_t stream)
{
    const float* state = (const float*)d_in[0];
    const float* noise = (const float*)d_in[1];
    const float* Wq  = (const float*)d_in[2];
    const float* Wk  = (const float*)d_in[3];
    const float* Wv  = (const float*)d_in[4];
    const float* W1  = (const float*)d_in[5];
    const float* b1  = (const float*)d_in[6];
    const float* W2  = (const float*)d_in[7];
    const float* b2  = (const float*)d_in[8];
    const float* Wmu = (const float*)d_in[9];
    const float* bmu = (const float*)d_in[10];
    const float* Wls = (const float*)d_in[11];
    const float* bls = (const float*)d_in[12];
    float* out = (float*)d_out;

    unsigned short* w1t = (unsigned short*)d_ws;       // 8192 bf16
    unsigned short* w2t = w1t + 8192;                  // 65536 bf16
    unsigned short* kbp = w2t + 65536;                 // 128*3*128*8 bf16
    unsigned short* vbp = kbp + 393216;                // same
    float*          qsp = (float*)(vbp + 393216);      // 128*128*24 fp32

    prep_kernel<<<dim3(164), dim3(256), 0, stream>>>(
        state, Wq, Wk, Wv, W1, W2, w1t, w2t, kbp, vbp, qsp);
    fused_actor_kernel<<<dim3(B_*4), dim3(256), 0, stream>>>(
        state, noise, kbp, vbp, qsp, w1t, b1, w2t, b2, Wmu, bmu, Wls, bls, out);
}

// Round 6
// 101.888 us; speedup vs baseline: 1.0948x; 1.0494x over previous
//
#include <hip/hip_runtime.h>
#include <math.h>

// Problem constants (RelTransformerActor)
namespace {
constexpr int B_  = 128;
constexpr int T_  = 128;
constexpr int K_  = 8;
constexpr int H_  = 3;
constexpr int HK_ = 24;
constexpr int HID_ = 256;
constexpr int OUT_ = 2;
}

typedef __attribute__((ext_vector_type(8))) short bf16x8;
typedef __attribute__((ext_vector_type(4))) float f32x4;

__device__ inline unsigned short f2bf(float x) {           // RNE fp32->bf16
    unsigned int u = __float_as_uint(x);
    u += 0x7FFFu + ((u >> 16) & 1u);
    return (unsigned short)(u >> 16);
}
__device__ inline float bflo(unsigned int u) { return __uint_as_float(u << 16); }
__device__ inline float bfhi(unsigned int u) { return __uint_as_float(u & 0xFFFF0000u); }

// Cross-lane add via DPP (VALU pipe, not DS).
template <int CTRL>
__device__ inline float dpp_add(float v) {
    int t = __builtin_amdgcn_update_dpp(0, __float_as_int(v), CTRL, 0xF, 0xF, true);
    return v + __int_as_float(t);
}
__device__ inline float red8(float v) {    // sum over 8-lane groups
    v = dpp_add<0xB1>(v);     // quad_perm lane^1
    v = dpp_add<0x4E>(v);     // quad_perm lane^2
    return dpp_add<0x141>(v); // row_half_mirror
}
__device__ inline float red16(float v) {   // sum over 16-lane groups
    return dpp_add<0x140>(red8(v));        // + row_mirror
}

// ---------------------------------------------------------------------------
// Prep: W1 [32][256] -> w1t bf16 [n][k=32]; W2 [256][256] -> w2t bf16 [n][k=256]
// (MFMA 16x16x32 B-frag needs k-contiguous rows per n). Coalesced reads over n.
// ---------------------------------------------------------------------------
__global__ __launch_bounds__(256) void prep_kernel(
    const float* __restrict__ W1, const float* __restrict__ W2,
    unsigned short* __restrict__ w1t, unsigned short* __restrict__ w2t)
{
    const int n = threadIdx.x;
    unsigned short tmp[8];
    if (blockIdx.x < 32) {
        const int k0 = blockIdx.x * 8;
        #pragma unroll
        for (int i = 0; i < 8; ++i) tmp[i] = f2bf(W2[(size_t)(k0+i)*HID_ + n]);
        *(bf16x8*)(w2t + (size_t)n*256 + k0) = *(const bf16x8*)tmp;
    } else {
        const int k0 = (blockIdx.x - 32) * 8;
        #pragma unroll
        for (int i = 0; i < 8; ++i) tmp[i] = f2bf(W1[(size_t)(k0+i)*HID_ + n]);
        *(bf16x8*)(w1t + (size_t)n*32 + k0) = *(const bf16x8*)tmp;
    }
}

// ---------------------------------------------------------------------------
// Fused actor. Block = (b, quarter of i): 32 query rows, 256 threads,
// grid 512 = 2 blocks/CU. In-block projections (thread-per-j, packed b128
// LDS writes), DPP reductions, MFMA MLP.
// Identities: softmax shift-invariance kills Kp[i]; sum w = 1 turns the
// Vp[i] term into a subtraction.
// ---------------------------------------------------------------------------
__global__ __launch_bounds__(256) void fused_actor_kernel(
    const float* __restrict__ state,
    const float* __restrict__ noise,
    const float* __restrict__ Wq, const float* __restrict__ Wk,
    const float* __restrict__ Wv,
    const unsigned short* __restrict__ w1t, const float* __restrict__ b1,
    const unsigned short* __restrict__ w2t, const float* __restrict__ b2,
    const float* __restrict__ Wmu, const float* __restrict__ bmu,
    const float* __restrict__ Wls, const float* __restrict__ bls,
    float* __restrict__ out)
{
    __shared__ float wq_s[K_*HK_], wk_s[K_*HK_], wv_s[K_*HK_]; // 2.25 KB
    __shared__ alignas(16) unsigned short Kb[H_][T_][8];     // 6 KB (row 16B)
    __shared__ alignas(16) unsigned short Vb[H_][T_][8];     // 6 KB
    __shared__ alignas(16) float Qs[32][HK_];                // 3 KB (row 96B)
    __shared__ alignas(16) unsigned short a0b[32][40];       // 2.5 KB (row 80B)
    __shared__ alignas(16) unsigned short x1s[32][264];      // 16.5 KB (row 528B)
    __shared__ alignas(16) float hp[4][32][4];               // 2 KB

    const int tid  = threadIdx.x;
    const int b    = blockIdx.x >> 2;
    const int iq   = blockIdx.x & 3;
    const int i0   = iq * 32;
    const int w    = tid >> 6;
    const int lane = tid & 63;
    const float* sb = state + (size_t)b*T_*K_;

    // ---- stage qkv weights (192 floats each) ----
    if (tid < K_*HK_) { wq_s[tid]=Wq[tid]; wk_s[tid]=Wk[tid]; wv_s[tid]=Wv[tid]; }
    __syncthreads();

    // ---- projections: thread = (j, K-or-V). Global float4 state reads,
    //      LDS weight broadcasts, one b128 LDS write per head. ----
    {
        const int j = tid >> 1, p = tid & 1;
        const float4 s0 = *(const float4*)(sb + j*8);
        const float4 s1 = *(const float4*)(sb + j*8 + 4);
        const float sv[8] = {s0.x,s0.y,s0.z,s0.w,s1.x,s1.y,s1.z,s1.w};
        const float* ws = p ? wv_s : wk_s;
        #pragma unroll
        for (int h = 0; h < H_; ++h) {
            unsigned short pk[8];
            #pragma unroll
            for (int k = 0; k < 8; ++k) {
                const int col = h*8 + k;
                float a = 0.f;
                #pragma unroll
                for (int m = 0; m < K_; ++m) a = fmaf(sv[m], ws[m*HK_+col], a);
                pk[k] = f2bf(a);
            }
            unsigned short* dst = p ? &Vb[h][j][0] : &Kb[h][j][0];
            *(bf16x8*)dst = *(const bf16x8*)pk;
        }
        // concat-state columns of a0b (block's own 32 rows), bf16-packed
        if (p == 0 && j >= i0 && j < i0 + 32) {
            unsigned short sb16[8];
            #pragma unroll
            for (int k = 0; k < 8; ++k) sb16[k] = f2bf(sv[k]);
            *(bf16x8*)&a0b[j - i0][HK_] = *(const bf16x8*)sb16;
        }
    }
    // ---- Q projection: thread covers 3 cols of one of the 32 rows ----
    {
        const int il = tid >> 3;
        const int c0 = (tid & 7) * 3;
        const float4 s0 = *(const float4*)(sb + (i0+il)*8);
        const float4 s1 = *(const float4*)(sb + (i0+il)*8 + 4);
        const float sv[8] = {s0.x,s0.y,s0.z,s0.w,s1.x,s1.y,s1.z,s1.w};
        #pragma unroll
        for (int cc = 0; cc < 3; ++cc) {
            const int col = c0 + cc;
            float aq = 0.f;
            #pragma unroll
            for (int m = 0; m < K_; ++m) aq = fmaf(sv[m], wq_s[m*HK_+col], aq);
            Qs[il][col] = aq * 0.35355339059327373f;
        }
    }
    __syncthreads();

    // ---- attention: lane=(i_sub*8+jg); 3 passes/wave; DPP 8-lane reduce ----
    {
        const int i_sub = lane >> 3, jg = lane & 7;
        #pragma unroll
        for (int p = 0; p < 3; ++p) {
            const int pair = w*3 + p;        // 0..11 : (h, group-of-8-i)
            const int h  = pair >> 2;        // wave-uniform
            const int ig = pair & 3;
            const int il = ig*8 + i_sub;
            const int iglob = i0 + il;
            const float4 q0 = *(const float4*)&Qs[il][h*8];
            const float4 q1 = *(const float4*)&Qs[il][h*8+4];
            float l = 0.f;
            float acc[8] = {0.f,0.f,0.f,0.f,0.f,0.f,0.f,0.f};
            #pragma unroll 4
            for (int t = 0; t < 16; ++t) {
                const int j = t*8 + jg;      // 8 lanes -> 128B contiguous
                const int4 kk = *(const int4*)&Kb[h][j][0];
                float s;
                s = q0.x * bflo(kk.x) + q0.y * bfhi(kk.x)
                  + q0.z * bflo(kk.y) + q0.w * bfhi(kk.y)
                  + q1.x * bflo(kk.z) + q1.y * bfhi(kk.z)
                  + q1.z * bflo(kk.w) + q1.w * bfhi(kk.w);
                const float e = (j == iglob) ? 0.f : __expf(s);
                l += e;
                const int4 vv = *(const int4*)&Vb[h][j][0];
                acc[0] = fmaf(e, bflo(vv.x), acc[0]);
                acc[1] = fmaf(e, bfhi(vv.x), acc[1]);
                acc[2] = fmaf(e, bflo(vv.y), acc[2]);
                acc[3] = fmaf(e, bfhi(vv.y), acc[3]);
                acc[4] = fmaf(e, bflo(vv.z), acc[4]);
                acc[5] = fmaf(e, bfhi(vv.z), acc[5]);
                acc[6] = fmaf(e, bflo(vv.w), acc[6]);
                acc[7] = fmaf(e, bfhi(vv.w), acc[7]);
            }
            l = red8(l);
            #pragma unroll
            for (int k = 0; k < 8; ++k) acc[k] = red8(acc[k]);
            if (jg == 0) {
                const float rl = 1.f / l;
                const int4 vi = *(const int4*)&Vb[h][iglob][0];
                const float vs[8] = { bflo(vi.x), bfhi(vi.x), bflo(vi.y), bfhi(vi.y),
                                      bflo(vi.z), bfhi(vi.z), bflo(vi.w), bfhi(vi.w) };
                unsigned int r01 = (unsigned int)f2bf(acc[0]*rl - vs[0])
                                 | ((unsigned int)f2bf(acc[1]*rl - vs[1]) << 16);
                unsigned int r23 = (unsigned int)f2bf(acc[2]*rl - vs[2])
                                 | ((unsigned int)f2bf(acc[3]*rl - vs[3]) << 16);
                unsigned int r45 = (unsigned int)f2bf(acc[4]*rl - vs[4])
                                 | ((unsigned int)f2bf(acc[5]*rl - vs[5]) << 16);
                unsigned int r67 = (unsigned int)f2bf(acc[6]*rl - vs[6])
                                 | ((unsigned int)f2bf(acc[7]*rl - vs[7]) << 16);
                int4 rr; rr.x = r01; rr.y = r23; rr.z = r45; rr.w = r67;
                *(int4*)&a0b[il][h*8] = rr;
            }
        }
    }
    __syncthreads();

    const int lq = (tid >> 4) & 3;   // MFMA k-chunk (A/B) / row-group (D)
    const int ln = tid & 15;         // MFMA m (A) / n (B,D)

    // ---- x1 = relu([x||state] @ W1 + b1) via MFMA, M=32 (2 tiles), K=32 ----
    {
        const bf16x8 a0 = *(const bf16x8*)&a0b[ln][lq*8];
        const bf16x8 a1 = *(const bf16x8*)&a0b[16+ln][lq*8];
        #pragma unroll
        for (int nt = 0; nt < 4; ++nt) {
            const int n0 = (w*4 + nt)*16;
            const bf16x8 bf = *(const bf16x8*)(w1t + (size_t)(n0+ln)*32 + lq*8);
            const float bias = b1[n0+ln];
            f32x4 c = {bias, bias, bias, bias};
            f32x4 d0 = __builtin_amdgcn_mfma_f32_16x16x32_bf16(a0, bf, c, 0, 0, 0);
            f32x4 d1 = __builtin_amdgcn_mfma_f32_16x16x32_bf16(a1, bf, c, 0, 0, 0);
            #pragma unroll
            for (int r = 0; r < 4; ++r) {
                x1s[lq*4 + r][n0+ln]      = f2bf(fmaxf(d0[r], 0.f));
                x1s[16 + lq*4 + r][n0+ln] = f2bf(fmaxf(d1[r], 0.f));
            }
        }
    }
    __syncthreads();

    // ---- x2 = relu(x1 @ W2 + b2) via MFMA: 2 M-tiles x 4 N-tiles x 8 k ----
    f32x4 acc2[2][4];
    #pragma unroll
    for (int nt = 0; nt < 4; ++nt) {
        const float bias = b2[(w*4+nt)*16 + ln];
        f32x4 c = {bias, bias, bias, bias};
        acc2[0][nt] = c; acc2[1][nt] = c;
    }
    #pragma unroll 2
    for (int ks = 0; ks < 8; ++ks) {
        const int k0 = ks*32;
        const bf16x8 a0 = *(const bf16x8*)&x1s[ln][k0 + lq*8];
        const bf16x8 a1 = *(const bf16x8*)&x1s[16+ln][k0 + lq*8];
        #pragma unroll
        for (int nt = 0; nt < 4; ++nt) {
            const bf16x8 bf = *(const bf16x8*)(w2t + (size_t)((w*4+nt)*16+ln)*256 + k0 + lq*8);
            acc2[0][nt] = __builtin_amdgcn_mfma_f32_16x16x32_bf16(a0, bf, acc2[0][nt], 0,0,0);
            acc2[1][nt] = __builtin_amdgcn_mfma_f32_16x16x32_bf16(a1, bf, acc2[1][nt], 0,0,0);
        }
    }

    // ---- heads: relu(x2).{Wmu,Wls}; DPP 16-lane reduce over n-lanes ----
    {
        float p[2][4][4];
        #pragma unroll
        for (int mt = 0; mt < 2; ++mt)
            #pragma unroll
            for (int r = 0; r < 4; ++r)
                #pragma unroll
                for (int o = 0; o < 4; ++o) p[mt][r][o] = 0.f;
        #pragma unroll
        for (int nt = 0; nt < 4; ++nt) {
            const int n = (w*4+nt)*16 + ln;
            const float2 wm = *(const float2*)(Wmu + n*OUT_);
            const float2 wl = *(const float2*)(Wls + n*OUT_);
            #pragma unroll
            for (int mt = 0; mt < 2; ++mt) {
                #pragma unroll
                for (int r = 0; r < 4; ++r) {
                    const float x2 = fmaxf(acc2[mt][nt][r], 0.f);
                    p[mt][r][0] = fmaf(x2, wm.x, p[mt][r][0]);
                    p[mt][r][1] = fmaf(x2, wm.y, p[mt][r][1]);
                    p[mt][r][2] = fmaf(x2, wl.x, p[mt][r][2]);
                    p[mt][r][3] = fmaf(x2, wl.y, p[mt][r][3]);
                }
            }
        }
        #pragma unroll
        for (int mt = 0; mt < 2; ++mt)
            #pragma unroll
            for (int r = 0; r < 4; ++r)
                #pragma unroll
                for (int o = 0; o < 4; ++o)
                    p[mt][r][o] = red16(p[mt][r][o]);
        if (ln == 0) {
            #pragma unroll
            for (int mt = 0; mt < 2; ++mt)
                #pragma unroll
                for (int r = 0; r < 4; ++r) {
                    f32x4 pv = {p[mt][r][0], p[mt][r][1], p[mt][r][2], p[mt][r][3]};
                    *(f32x4*)&hp[w][mt*16 + lq*4 + r][0] = pv;
                }
        }
    }
    __syncthreads();

    // ---- sampling tail: one thread per row ----
    if (tid < 32) {
        const int r = tid;
        const int grow = b*T_ + i0 + r;
        float pre[4];
        #pragma unroll
        for (int o = 0; o < 4; ++o)
            pre[o] = hp[0][r][o] + hp[1][r][o] + hp[2][r][o] + hp[3][r][o];
        float lp = 0.f;
        #pragma unroll
        for (int o = 0; o < OUT_; ++o) {
            float mu  = tanhf(pre[o]   + bmu[o]);
            float lsp = tanhf(pre[2+o] + bls[o]);
            float log_std = -20.f + 11.f * (lsp + 1.f);
            float sd = __expf(log_std);
            float n  = noise[(size_t)grow*OUT_ + o];
            float z  = fmaf(sd, n, mu);
            float a  = tanhf(z);
            out[(size_t)grow*OUT_ + o] = a;
            lp += -0.5f*n*n - log_std - 0.91893853320467274f
                  - logf(1.f - a*a + 1e-7f);
        }
        out[(size_t)B_*T_*OUT_ + grow] = lp;
    }
}

extern "C" void kernel_launch(void* const* d_in, const int* in_sizes, int n_in,
                              void* d_out, int out_size, void* d_ws, size_t ws_size,
                              hipStream_t stream)
{
    const float* state = (const float*)d_in[0];
    const float* noise = (const float*)d_in[1];
    const float* Wq  = (const float*)d_in[2];
    const float* Wk  = (const float*)d_in[3];
    const float* Wv  = (const float*)d_in[4];
    const float* W1  = (const float*)d_in[5];
    const float* b1  = (const float*)d_in[6];
    const float* W2  = (const float*)d_in[7];
    const float* b2  = (const float*)d_in[8];
    const float* Wmu = (const float*)d_in[9];
    const float* bmu = (const float*)d_in[10];
    const float* Wls = (const float*)d_in[11];
    const float* bls = (const float*)d_in[12];
    float* out = (float*)d_out;

    unsigned short* w1t = (unsigned short*)d_ws;       // 8192 bf16
    unsigned short* w2t = w1t + 8192;                  // 65536 bf16

    prep_kernel<<<dim3(36), dim3(256), 0, stream>>>(W1, W2, w1t, w2t);
    fused_actor_kernel<<<dim3(B_*4), dim3(256), 0, stream>>>(
        state, noise, Wq, Wk, Wv, w1t, b1, w2t, b2, Wmu, bmu, Wls, bls, out);
}

// Round 7
// 95.660 us; speedup vs baseline: 1.1660x; 1.0651x over previous
//
#include <hip/hip_runtime.h>
#include <math.h>

// Problem constants (RelTransformerActor)
namespace {
constexpr int B_  = 128;
constexpr int T_  = 128;
constexpr int K_  = 8;
constexpr int H_  = 3;
constexpr int HK_ = 24;
constexpr int HID_ = 256;
constexpr int OUT_ = 2;
constexpr int PBS_ = 144;  // Pb row stride (bf16): 288B = 16B-aligned, banks spread
}

typedef __attribute__((ext_vector_type(8))) short bf16x8;
typedef __attribute__((ext_vector_type(4))) float f32x4;

__device__ inline unsigned short f2bf(float x) {           // RNE fp32->bf16
    unsigned int u = __float_as_uint(x);
    u += 0x7FFFu + ((u >> 16) & 1u);
    return (unsigned short)(u >> 16);
}
__device__ inline float bf2f(unsigned short v) { return __uint_as_float((unsigned)v << 16); }

// Cross-lane add via DPP (VALU pipe, not DS).
template <int CTRL>
__device__ inline float dpp_add(float v) {
    int t = __builtin_amdgcn_update_dpp(0, __float_as_int(v), CTRL, 0xF, 0xF, true);
    return v + __int_as_float(t);
}
__device__ inline float red16(float v) {   // sum over 16-lane groups
    v = dpp_add<0xB1>(v);     // quad_perm lane^1
    v = dpp_add<0x4E>(v);     // quad_perm lane^2
    v = dpp_add<0x141>(v);    // row_half_mirror
    return dpp_add<0x140>(v); // row_mirror
}

// ---------------------------------------------------------------------------
// Prep: W1 [32][256] -> w1t bf16 [n][k=32]; W2 [256][256] -> w2t bf16 [n][k=256]
// (MFMA 16x16x32 B-frag needs k-contiguous rows per n). Coalesced reads over n.
// ---------------------------------------------------------------------------
__global__ __launch_bounds__(256) void prep_kernel(
    const float* __restrict__ W1, const float* __restrict__ W2,
    unsigned short* __restrict__ w1t, unsigned short* __restrict__ w2t)
{
    const int n = threadIdx.x;
    unsigned short tmp[8];
    if (blockIdx.x < 32) {
        const int k0 = blockIdx.x * 8;
        #pragma unroll
        for (int i = 0; i < 8; ++i) tmp[i] = f2bf(W2[(size_t)(k0+i)*HID_ + n]);
        *(bf16x8*)(w2t + (size_t)n*256 + k0) = *(const bf16x8*)tmp;
    } else {
        const int k0 = (blockIdx.x - 32) * 8;
        #pragma unroll
        for (int i = 0; i < 8; ++i) tmp[i] = f2bf(W1[(size_t)(k0+i)*HID_ + n]);
        *(bf16x8*)(w1t + (size_t)n*32 + k0) = *(const bf16x8*)tmp;
    }
}

// ---------------------------------------------------------------------------
// Fused actor. Block = (b, quarter of i): 32 query rows, 256 threads,
// grid 512 = 2 blocks/CU. Attention via MFMA (flash-style, exact: all T=128
// keys in LDS). Identities: softmax shift-invariance kills Kp[i]; sum w = 1
// turns the Vp[i] term into a subtraction.
// ---------------------------------------------------------------------------
__global__ __launch_bounds__(256) void fused_actor_kernel(
    const float* __restrict__ state,
    const float* __restrict__ noise,
    const float* __restrict__ Wq, const float* __restrict__ Wk,
    const float* __restrict__ Wv,
    const unsigned short* __restrict__ w1t, const float* __restrict__ b1,
    const unsigned short* __restrict__ w2t, const float* __restrict__ b2,
    const float* __restrict__ Wmu, const float* __restrict__ bmu,
    const float* __restrict__ Wls, const float* __restrict__ bls,
    float* __restrict__ out)
{
    __shared__ float wq_s[K_*HK_], wk_s[K_*HK_], wv_s[K_*HK_]; // 2.25 KB
    __shared__ alignas(16) unsigned short Qb[32][HK_];       // 1.5 KB (row 48B)
    __shared__ alignas(16) unsigned short Kb[H_][T_][8];     // 6 KB (row 16B)
    __shared__ alignas(16) unsigned short Vt[H_][K_][T_];    // 6 KB (row 256B)
    __shared__ alignas(16) float lsum[4][H_][32];            // 1.5 KB
    __shared__ alignas(16) unsigned short a0b[32][40];       // 2.5 KB (row 80B)
    __shared__ union alignas(16) {
        unsigned short Pb[H_][32][PBS_];                     // 27 KB (row 288B)
        unsigned short x1s[32][264];                         // 16.5 KB
    } u;
    __shared__ alignas(16) float hp[4][32][4];               // 2 KB

    const int tid  = threadIdx.x;
    const int b    = blockIdx.x >> 2;
    const int iq   = blockIdx.x & 3;
    const int i0   = iq * 32;
    const int w    = tid >> 6;
    const int lq   = (tid >> 4) & 3;   // MFMA quad: k-chunk (A/B) / row-group (C/D)
    const int ln   = tid & 15;         // MFMA m (A) / n (B, C/D cols)
    const float* sb = state + (size_t)b*T_*K_;

    // ---- stage qkv weights ----
    if (tid < K_*HK_) { wq_s[tid]=Wq[tid]; wk_s[tid]=Wk[tid]; wv_s[tid]=Wv[tid]; }
    __syncthreads();

    // ---- projections: thread = (j, K-or-V) ----
    {
        const int j = tid >> 1, p = tid & 1;
        const float4 s0 = *(const float4*)(sb + j*8);
        const float4 s1 = *(const float4*)(sb + j*8 + 4);
        const float sv[8] = {s0.x,s0.y,s0.z,s0.w,s1.x,s1.y,s1.z,s1.w};
        const float* ws = p ? wv_s : wk_s;
        #pragma unroll
        for (int h = 0; h < H_; ++h) {
            unsigned short pk[8];
            #pragma unroll
            for (int k = 0; k < 8; ++k) {
                const int col = h*8 + k;
                float a = 0.f;
                #pragma unroll
                for (int m = 0; m < K_; ++m) a = fmaf(sv[m], ws[m*HK_+col], a);
                pk[k] = f2bf(a);
            }
            if (p == 0) {
                *(bf16x8*)&Kb[h][j][0] = *(const bf16x8*)pk;
            } else {
                #pragma unroll
                for (int d = 0; d < 8; ++d) Vt[h][d][j] = pk[d];  // transposed V
            }
        }
        // concat-state columns of a0b (block's own 32 rows), bf16-packed
        if (p == 0 && j >= i0 && j < i0 + 32) {
            unsigned short sb16[8];
            #pragma unroll
            for (int k = 0; k < 8; ++k) sb16[k] = f2bf(sv[k]);
            *(bf16x8*)&a0b[j - i0][HK_] = *(const bf16x8*)sb16;
        }
    }
    // ---- Q projection (bf16, pre-scaled 1/sqrt(8)): 3 cols per thread ----
    {
        const int il = tid >> 3;
        const int c0 = (tid & 7) * 3;
        const float4 s0 = *(const float4*)(sb + (i0+il)*8);
        const float4 s1 = *(const float4*)(sb + (i0+il)*8 + 4);
        const float sv[8] = {s0.x,s0.y,s0.z,s0.w,s1.x,s1.y,s1.z,s1.w};
        #pragma unroll
        for (int cc = 0; cc < 3; ++cc) {
            const int col = c0 + cc;
            float aq = 0.f;
            #pragma unroll
            for (int m = 0; m < K_; ++m) aq = fmaf(sv[m], wq_s[m*HK_+col], aq);
            Qb[il][col] = f2bf(aq * 0.35355339059327373f);
        }
    }
    __syncthreads();

    // ---- S = Q@K^T via MFMA (K-dim 8 padded to 32 by lane-select zeros) ----
    // Wave w owns n-tiles {2w, 2w+1}; exp + mask in C-layout; P -> LDS (bf16);
    // per-wave row-sum partials via DPP red16 -> lsum[w].
    {
        const bf16x8 zf = {0,0,0,0,0,0,0,0};
        const f32x4 c0v = {0.f,0.f,0.f,0.f};
        float esum[H_][2][4];
        #pragma unroll
        for (int h = 0; h < H_; ++h)
            #pragma unroll
            for (int mt = 0; mt < 2; ++mt)
                #pragma unroll
                for (int r = 0; r < 4; ++r) esum[h][mt][r] = 0.f;
        #pragma unroll
        for (int h = 0; h < H_; ++h) {
            bf16x8 qa[2];
            #pragma unroll
            for (int mt = 0; mt < 2; ++mt) {
                const bf16x8 t = *(const bf16x8*)&Qb[mt*16 + ln][h*8];
                qa[mt] = (lq == 0) ? t : zf;
            }
            #pragma unroll
            for (int nti = 0; nti < 2; ++nti) {
                const int nt = w*2 + nti;
                const bf16x8 tb = *(const bf16x8*)&Kb[h][nt*16 + ln][0];
                const bf16x8 kf = (lq == 0) ? tb : zf;
                #pragma unroll
                for (int mt = 0; mt < 2; ++mt) {
                    f32x4 s = __builtin_amdgcn_mfma_f32_16x16x32_bf16(qa[mt], kf, c0v, 0,0,0);
                    #pragma unroll
                    for (int r = 0; r < 4; ++r) {
                        const int il = mt*16 + lq*4 + r;
                        const int j  = nt*16 + ln;
                        const float e = (j == i0 + il) ? 0.f : __expf(s[r]);
                        esum[h][mt][r] += e;
                        u.Pb[h][il][j] = f2bf(e);
                    }
                }
            }
        }
        #pragma unroll
        for (int h = 0; h < H_; ++h)
            #pragma unroll
            for (int mt = 0; mt < 2; ++mt)
                #pragma unroll
                for (int r = 0; r < 4; ++r) {
                    const float v = red16(esum[h][mt][r]);
                    if (ln == 0) lsum[w][h][mt*16 + lq*4 + r] = v;
                }
    }
    __syncthreads();

    // ---- X = P@V via MFMA (M=32, N=8 pad 16, K=128); epilogue: /l - Vp[i] ----
    {
        const bf16x8 zf = {0,0,0,0,0,0,0,0};
        for (int id = w; id < 6; id += 4) {          // item = (h, m-tile)
            const int h = id >> 1, mt = id & 1;
            f32x4 x = {0.f,0.f,0.f,0.f};
            #pragma unroll
            for (int ks = 0; ks < 4; ++ks) {
                const int k0 = ks*32;
                const bf16x8 pa = *(const bf16x8*)&u.Pb[h][mt*16 + ln][k0 + lq*8];
                const bf16x8 tv = *(const bf16x8*)&Vt[h][ln & 7][k0 + lq*8];
                const bf16x8 vf = (ln < 8) ? tv : zf;
                x = __builtin_amdgcn_mfma_f32_16x16x32_bf16(pa, vf, x, 0, 0, 0);
            }
            if (ln < 8) {
                #pragma unroll
                for (int r = 0; r < 4; ++r) {
                    const int il = mt*16 + lq*4 + r;
                    const float l = lsum[0][h][il] + lsum[1][h][il]
                                  + lsum[2][h][il] + lsum[3][h][il];
                    const float xatt = x[r] / l - bf2f(Vt[h][ln][i0 + il]);
                    a0b[il][h*8 + ln] = f2bf(xatt);
                }
            }
        }
    }
    __syncthreads();   // a0b complete; Pb dead -> x1s may reuse union

    // ---- x1 = relu([x||state] @ W1 + b1) via MFMA, M=32 (2 tiles), K=32 ----
    {
        const bf16x8 a0 = *(const bf16x8*)&a0b[ln][lq*8];
        const bf16x8 a1 = *(const bf16x8*)&a0b[16+ln][lq*8];
        #pragma unroll
        for (int nt = 0; nt < 4; ++nt) {
            const int n0 = (w*4 + nt)*16;
            const bf16x8 bf = *(const bf16x8*)(w1t + (size_t)(n0+ln)*32 + lq*8);
            const float bias = b1[n0+ln];
            f32x4 c = {bias, bias, bias, bias};
            f32x4 d0 = __builtin_amdgcn_mfma_f32_16x16x32_bf16(a0, bf, c, 0, 0, 0);
            f32x4 d1 = __builtin_amdgcn_mfma_f32_16x16x32_bf16(a1, bf, c, 0, 0, 0);
            #pragma unroll
            for (int r = 0; r < 4; ++r) {
                u.x1s[lq*4 + r][n0+ln]      = f2bf(fmaxf(d0[r], 0.f));
                u.x1s[16 + lq*4 + r][n0+ln] = f2bf(fmaxf(d1[r], 0.f));
            }
        }
    }
    __syncthreads();

    // ---- x2 = relu(x1 @ W2 + b2) via MFMA: 2 M-tiles x 4 N-tiles x 8 k ----
    f32x4 acc2[2][4];
    #pragma unroll
    for (int nt = 0; nt < 4; ++nt) {
        const float bias = b2[(w*4+nt)*16 + ln];
        f32x4 c = {bias, bias, bias, bias};
        acc2[0][nt] = c; acc2[1][nt] = c;
    }
    #pragma unroll 2
    for (int ks = 0; ks < 8; ++ks) {
        const int k0 = ks*32;
        const bf16x8 a0 = *(const bf16x8*)&u.x1s[ln][k0 + lq*8];
        const bf16x8 a1 = *(const bf16x8*)&u.x1s[16+ln][k0 + lq*8];
        #pragma unroll
        for (int nt = 0; nt < 4; ++nt) {
            const bf16x8 bf = *(const bf16x8*)(w2t + (size_t)((w*4+nt)*16+ln)*256 + k0 + lq*8);
            acc2[0][nt] = __builtin_amdgcn_mfma_f32_16x16x32_bf16(a0, bf, acc2[0][nt], 0,0,0);
            acc2[1][nt] = __builtin_amdgcn_mfma_f32_16x16x32_bf16(a1, bf, acc2[1][nt], 0,0,0);
        }
    }

    // ---- heads: relu(x2).{Wmu,Wls}; DPP 16-lane reduce over n-lanes ----
    {
        float p[2][4][4];
        #pragma unroll
        for (int mt = 0; mt < 2; ++mt)
            #pragma unroll
            for (int r = 0; r < 4; ++r)
                #pragma unroll
                for (int o = 0; o < 4; ++o) p[mt][r][o] = 0.f;
        #pragma unroll
        for (int nt = 0; nt < 4; ++nt) {
            const int n = (w*4+nt)*16 + ln;
            const float2 wm = *(const float2*)(Wmu + n*OUT_);
            const float2 wl = *(const float2*)(Wls + n*OUT_);
            #pragma unroll
            for (int mt = 0; mt < 2; ++mt) {
                #pragma unroll
                for (int r = 0; r < 4; ++r) {
                    const float x2 = fmaxf(acc2[mt][nt][r], 0.f);
                    p[mt][r][0] = fmaf(x2, wm.x, p[mt][r][0]);
                    p[mt][r][1] = fmaf(x2, wm.y, p[mt][r][1]);
                    p[mt][r][2] = fmaf(x2, wl.x, p[mt][r][2]);
                    p[mt][r][3] = fmaf(x2, wl.y, p[mt][r][3]);
                }
            }
        }
        #pragma unroll
        for (int mt = 0; mt < 2; ++mt)
            #pragma unroll
            for (int r = 0; r < 4; ++r)
                #pragma unroll
                for (int o = 0; o < 4; ++o)
                    p[mt][r][o] = red16(p[mt][r][o]);
        if (ln == 0) {
            #pragma unroll
            for (int mt = 0; mt < 2; ++mt)
                #pragma unroll
                for (int r = 0; r < 4; ++r) {
                    f32x4 pv = {p[mt][r][0], p[mt][r][1], p[mt][r][2], p[mt][r][3]};
                    *(f32x4*)&hp[w][mt*16 + lq*4 + r][0] = pv;
                }
        }
    }
    __syncthreads();

    // ---- sampling tail: one thread per row ----
    if (tid < 32) {
        const int r = tid;
        const int grow = b*T_ + i0 + r;
        float pre[4];
        #pragma unroll
        for (int o = 0; o < 4; ++o)
            pre[o] = hp[0][r][o] + hp[1][r][o] + hp[2][r][o] + hp[3][r][o];
        float lp = 0.f;
        #pragma unroll
        for (int o = 0; o < OUT_; ++o) {
            float mu  = tanhf(pre[o]   + bmu[o]);
            float lsp = tanhf(pre[2+o] + bls[o]);
            float log_std = -20.f + 11.f * (lsp + 1.f);
            float sd = __expf(log_std);
            float n  = noise[(size_t)grow*OUT_ + o];
            float z  = fmaf(sd, n, mu);
            float a  = tanhf(z);
            out[(size_t)grow*OUT_ + o] = a;
            lp += -0.5f*n*n - log_std - 0.91893853320467274f
                  - logf(1.f - a*a + 1e-7f);
        }
        out[(size_t)B_*T_*OUT_ + grow] = lp;
    }
}

extern "C" void kernel_launch(void* const* d_in, const int* in_sizes, int n_in,
                              void* d_out, int out_size, void* d_ws, size_t ws_size,
                              hipStream_t stream)
{
    const float* state = (const float*)d_in[0];
    const float* noise = (const float*)d_in[1];
    const float* Wq  = (const float*)d_in[2];
    const float* Wk  = (const float*)d_in[3];
    const float* Wv  = (const float*)d_in[4];
    const float* W1  = (const float*)d_in[5];
    const float* b1  = (const float*)d_in[6];
    const float* W2  = (const float*)d_in[7];
    const float* b2  = (const float*)d_in[8];
    const float* Wmu = (const float*)d_in[9];
    const float* bmu = (const float*)d_in[10];
    const float* Wls = (const float*)d_in[11];
    const float* bls = (const float*)d_in[12];
    float* out = (float*)d_out;

    unsigned short* w1t = (unsigned short*)d_ws;       // 8192 bf16
    unsigned short* w2t = w1t + 8192;                  // 65536 bf16

    prep_kernel<<<dim3(36), dim3(256), 0, stream>>>(W1, W2, w1t, w2t);
    fused_actor_kernel<<<dim3(B_*4), dim3(256), 0, stream>>>(
        state, noise, Wq, Wk, Wv, w1t, b1, w2t, b2, Wmu, bmu, Wls, bls, out);
}